// Round 1
// baseline (177.808 us; speedup 1.0000x reference)
//
#include <hip/hip_runtime.h>

#define B_SAMPLES 8192
#define NHID 256
#define NCLASSES 14

// ---------------- Kernel 1: exclusive prefix sum of lengths -> bounds[B+1] --
__global__ __launch_bounds__(256) void scan_lengths_kernel(
    const int* __restrict__ lengths, int* __restrict__ bounds)
{
    __shared__ int s_sum[256];
    const int t = threadIdx.x;
    // 8192 = 256 threads * 32 elems
    int local[32];
    int sum = 0;
#pragma unroll
    for (int k = 0; k < 32; ++k) {
        int v = lengths[t * 32 + k];
        local[k] = v;
        sum += v;
    }
    s_sum[t] = sum;
    __syncthreads();
    // Hillis-Steele inclusive scan over 256 partial sums
    for (int off = 1; off < 256; off <<= 1) {
        int v = (t >= off) ? s_sum[t - off] : 0;
        __syncthreads();
        s_sum[t] += v;
        __syncthreads();
    }
    int run = (t > 0) ? s_sum[t - 1] : 0;  // exclusive prefix for this chunk
#pragma unroll
    for (int k = 0; k < 32; ++k) {
        bounds[t * 32 + k] = run;
        run += local[k];
    }
    if (t == 255) bounds[B_SAMPLES] = run;  // == T
}

// ---------------- Kernel 2: per-sample gather-mean + tanh + [256x14] matmul -
__global__ __launch_bounds__(256, 8) void seg_mean_head_kernel(
    const int* __restrict__ indices,
    const float* __restrict__ emb,
    const float* __restrict__ W,
    const float* __restrict__ bias,
    const int* __restrict__ bounds,
    float* __restrict__ out)
{
    const int i = blockIdx.x;
    const int start = bounds[i];
    const int L = bounds[i + 1] - start;
    const int tid = threadIdx.x;
    const int sub = tid >> 6;   // which of 4 tokens in a group
    const int lane = tid & 63;  // 64 lanes x float4 = 256 floats (one emb row)

    __shared__ int s_idx[256];
    __shared__ float s_red[4 * NHID];
    __shared__ float s_t[NHID];

    float ax = 0.f, ay = 0.f, az = 0.f, aw = 0.f;

    for (int t0 = 0; t0 < L; t0 += 256) {
        const int n = min(256, L - t0);
        __syncthreads();  // protect s_idx from previous chunk's readers
        if (tid < n) s_idx[tid] = indices[start + t0 + tid];
        __syncthreads();

        int j = 0;
        // unroll x2: 8 tokens per iteration, 2 independent 16B loads per lane
        for (; j + 8 <= n; j += 8) {
            const int r0 = s_idx[j + sub];
            const int r1 = s_idx[j + 4 + sub];
            const float4 v0 = *reinterpret_cast<const float4*>(
                emb + (size_t)r0 * NHID + lane * 4);
            const float4 v1 = *reinterpret_cast<const float4*>(
                emb + (size_t)r1 * NHID + lane * 4);
            ax += v0.x + v1.x;
            ay += v0.y + v1.y;
            az += v0.z + v1.z;
            aw += v0.w + v1.w;
        }
        // tail: groups of up to 4 tokens
        for (; j < n; j += 4) {
            if (j + sub < n) {
                const int r = s_idx[j + sub];
                const float4 v = *reinterpret_cast<const float4*>(
                    emb + (size_t)r * NHID + lane * 4);
                ax += v.x; ay += v.y; az += v.z; aw += v.w;
            }
        }
    }

    // reduce the 4 token-sub accumulators per hidden dim
    s_red[sub * NHID + lane * 4 + 0] = ax;
    s_red[sub * NHID + lane * 4 + 1] = ay;
    s_red[sub * NHID + lane * 4 + 2] = az;
    s_red[sub * NHID + lane * 4 + 3] = aw;
    __syncthreads();

    const float tot = s_red[0 * NHID + tid] + s_red[1 * NHID + tid] +
                      s_red[2 * NHID + tid] + s_red[3 * NHID + tid];
    const float mean = (L > 0) ? tot / (float)L : 0.f;
    s_t[tid] = tanhf(mean);
    __syncthreads();

    // out[i][c] = sum_h tanh(mean_h) * W[h][c] + b[c]
    // 14 classes x 16 lanes each (threads 0..223)
    if (tid < 16 * NCLASSES) {
        const int c = tid >> 4;
        const int j = tid & 15;
        float p = 0.f;
#pragma unroll
        for (int k = 0; k < NHID / 16; ++k) {
            const int h = j + k * 16;
            p += s_t[h] * W[h * NCLASSES + c];
        }
#pragma unroll
        for (int off = 8; off > 0; off >>= 1) p += __shfl_down(p, off, 16);
        if (j == 0) out[(size_t)i * NCLASSES + c] = p + bias[c];
    }
}

extern "C" void kernel_launch(void* const* d_in, const int* in_sizes, int n_in,
                              void* d_out, int out_size, void* d_ws, size_t ws_size,
                              hipStream_t stream) {
    const int*   lengths = (const int*)d_in[0];
    const int*   indices = (const int*)d_in[1];
    const float* emb     = (const float*)d_in[2];
    const float* W       = (const float*)d_in[3];
    const float* bias    = (const float*)d_in[4];
    float*       out     = (float*)d_out;
    int*         bounds  = (int*)d_ws;  // B+1 ints

    scan_lengths_kernel<<<1, 256, 0, stream>>>(lengths, bounds);
    seg_mean_head_kernel<<<B_SAMPLES, 256, 0, stream>>>(
        indices, emb, W, bias, bounds, out);
}